// Round 5
// baseline (43.273 us; speedup 1.0000x reference)
//
#include <hip/hip_runtime.h>
#include <math.h>

#define TT 512
#define KP 4

typedef unsigned long long u64;

// one block = 4 rows (b, n0..n0+3), processed as 2 supersteps of a row-pair.
// 512 blocks x 256 threads. Stores of superstep s drain under compute of s+1.
__global__ __launch_bounds__(256) void periodicity_kernel(const float* __restrict__ x,
                                                          float* __restrict__ out) {
    const int blk  = blockIdx.x;     // 0..511
    const int tid  = threadIdx.x;    // 0..255
    const int lane = tid & 63;
    const int wid  = tid >> 6;
    const int b  = blk >> 4;         // 0..31
    const int n0 = (blk & 15) << 2;  // 0,4,...,60

    __shared__ float2 tw[TT];          // tw[m] = e^{-2*pi*i*m/512}
    __shared__ float  rowl[2][TT];     // natural-order rows of current pair
    __shared__ float2 buf[2][TT];      // FFT working buffers
    __shared__ u64    keys[2][256];    // packed (mag_bits<<32)|(255-(f-1))
    __shared__ int    fin8[2][8];
    __shared__ double candV8[2][8];

    // twiddles (one sincosf per thread); also kept in regs for the fold
    float sv, cv;
    sincosf((float)(2.0 * M_PI / 512.0) * (float)tid, &sv, &cv);
    tw[tid]       = make_float2(cv, -sv);
    tw[tid + 256] = make_float2(-cv, sv);

    // prefetch all 4 rows: thread tid holds x[b, tid, n0..n0+3] and x[b, tid+256, n0..n0+3]
    const float* xb = x + (size_t)b * (TT * 64) + n0;
    float4 ldA = *(const float4*)(xb + (size_t)tid * 64);
    float4 ldB = *(const float4*)(xb + (size_t)(tid + 256) * 64);

    const size_t VOFF = (size_t)2048 * KP * 64 * 64;   // 33,554,432

    #pragma unroll
    for (int ss = 0; ss < 2; ++ss) {
        __syncthreads();   // protects LDS reuse from previous superstep (and tw on ss=0)

        // ---- fold radix-2 first DIF stage into LDS write (both rows) ----
        #pragma unroll
        for (int rr = 0; rr < 2; ++rr) {
            const int rg = ss * 2 + rr;
            float v0 = ((const float*)&ldA)[rg];
            float v1 = ((const float*)&ldB)[rg];
            rowl[rr][tid] = v0;  rowl[rr][tid + 256] = v1;
            float sum = v0 + v1, dif = v0 - v1;
            buf[rr][tid]       = make_float2(sum, 0.f);
            buf[rr][tid + 256] = make_float2(dif * cv, -dif * sv);
        }
        __syncthreads();

        // ---- 4 radix-4 DIF stages, 2 rows in parallel (all 256 threads) ----
        {
            const int frr = tid >> 7;         // row of this thread
            const int fh  = (tid >> 6) & 1;   // which 256-half
            const int fj  = tid & 63;         // butterfly index in half
            float2* bb = &buf[frr][fh << 8];
            #pragma unroll
            for (int stg = 0; stg < 4; ++stg) {
                const int Q  = 64 >> (2 * stg);          // 64,16,4,1
                const int B4 = Q << 2;
                const int g  = fj >> (6 - 2 * stg);
                const int i  = fj & (Q - 1);
                const int base = g * B4 + i;
                float2 x0 = bb[base],         x1 = bb[base + Q];
                float2 x2 = bb[base + 2 * Q], x3 = bb[base + 3 * Q];
                float2 A  = make_float2(x0.x + x2.x, x0.y + x2.y);
                float2 Bm = make_float2(x0.x - x2.x, x0.y - x2.y);
                float2 Cc = make_float2(x1.x + x3.x, x1.y + x3.y);
                float2 D  = make_float2(x1.x - x3.x, x1.y - x3.y);
                float2 y0 = make_float2(A.x + Cc.x, A.y + Cc.y);
                float2 y2 = make_float2(A.x - Cc.x, A.y - Cc.y);
                float2 y1 = make_float2(Bm.x + D.y, Bm.y - D.x);   // Bm - i*D
                float2 y3 = make_float2(Bm.x - D.y, Bm.y + D.x);   // Bm + i*D
                const int m = i << (1 + 2 * stg);
                float2 t1 = tw[m], t2 = tw[2 * m], t3 = tw[3 * m];
                bb[base]         = y0;
                bb[base + Q]     = make_float2(y1.x * t1.x - y1.y * t1.y, y1.x * t1.y + y1.y * t1.x);
                bb[base + 2 * Q] = make_float2(y2.x * t2.x - y2.y * t2.y, y2.x * t2.y + y2.y * t2.x);
                bb[base + 3 * Q] = make_float2(y3.x * t3.x - y3.y * t3.y, y3.x * t3.y + y3.y * t3.x);
                __syncthreads();
            }
        }

        // ---- scatter |X|^2 into packed keys (base-4 digit-reversed order) ----
        {
            const int p  = tid;
            const int kp = ((p & 3) << 6) | (((p >> 2) & 3) << 4) | (((p >> 4) & 3) << 2) | ((p >> 6) & 3);
            #pragma unroll
            for (int q = 0; q < 4; ++q) {
                const int rr = q >> 1, hh = q & 1;
                const int f = 2 * kp + hh;
                if (f >= 1 && f <= 256) {
                    float2 v = buf[rr][hh * 256 + p];
                    float mag = v.x * v.x + v.y * v.y;
                    keys[rr][f - 1] = ((u64)__float_as_uint(mag) << 32) | (u64)(255 - (f - 1));
                }
            }
        }
        __syncthreads();

        // ---- top-8 per row: wave0 -> row0, wave1 -> row1 ----
        if (wid < 2) {
            const int rr = wid;
            u64 k0 = keys[rr][lane * 4 + 0];
            u64 k1 = keys[rr][lane * 4 + 1];
            u64 k2 = keys[rr][lane * 4 + 2];
            u64 k3 = keys[rr][lane * 4 + 3];
            #define CSWAP(a, b) { if (a < b) { u64 _t = a; a = b; b = _t; } }
            CSWAP(k0, k1) CSWAP(k2, k3) CSWAP(k0, k2) CSWAP(k1, k3) CSWAP(k1, k2)
            #undef CSWAP
            #pragma unroll
            for (int r = 0; r < 8; ++r) {
                u64 w = k0;
                #pragma unroll
                for (int off = 32; off >= 1; off >>= 1) {
                    u64 o = __shfl_xor(w, off);
                    if (o > w) w = o;
                }
                if (k0 == w) { k0 = k1; k1 = k2; k2 = k3; k3 = 0; }
                if (lane == 0) fin8[rr][r] = 256 - (int)(w & 0xff);
            }
        }
        __syncthreads();

        // ---- f64 refine: 16 groups of 16 threads (2 rows x 8 candidates) ----
        {
            const int cidg = tid >> 4;       // 0..15
            const int rr   = cidg >> 3;
            const int cand = cidg & 7;
            const int sub  = tid & 15;       // 32 samples per thread
            const int fc = fin8[rr][cand];
            const int t0 = sub * 32;
            const double W = 6.2831853071795864769 / 512.0;
            double zr, zi, wr, wi;
            sincos(W * (double)((fc * t0) & 511), &zi, &zr);
            sincos(W * (double)fc, &wi, &wr);
            double ar = 0.0, ai = 0.0;
            const float4* r4 = (const float4*)rowl[rr];
            #pragma unroll
            for (int v4i = 0; v4i < 8; ++v4i) {
                float4 xv = r4[sub * 8 + v4i];
                #define STEP(comp)                                   \
                    { double xd = (double)xv.comp;                   \
                      ar = fma(xd, zr, ar); ai = fma(xd, zi, ai);    \
                      double tq = zr * wr - zi * wi;                 \
                      zi = fma(zr, wi, zi * wr); zr = tq; }
                STEP(x) STEP(y) STEP(z) STEP(w)
                #undef STEP
            }
            #pragma unroll
            for (int off = 8; off >= 1; off >>= 1) {
                ar += __shfl_xor(ar, off);
                ai += __shfl_xor(ai, off);
            }
            if (sub == 0) candV8[rr][cand] = ar * ar + ai * ai;
        }
        __syncthreads();

        // ---- per row: final top-4, params, gather + store (no trailing waitcnt) ----
        #pragma unroll
        for (int rr = 0; rr < 2; ++rr) {
            const int rg = ss * 2 + rr;
            const int bn = b * 64 + n0 + rg;
            int per[KP], cycv[KP], st[KP];
            unsigned chosen = 0;
            #pragma unroll
            for (int k = 0; k < KP; ++k) {
                double bv = -1.0; int bbin = 0x7fffffff; int bj = 0;
                #pragma unroll
                for (int j = 0; j < 8; ++j) {
                    if (chosen & (1u << j)) continue;
                    double vj = candV8[rr][j];
                    int    bjn = fin8[rr][j];
                    if (vj > bv || (vj == bv && bjn < bbin)) { bv = vj; bbin = bjn; bj = j; }
                }
                chosen |= (1u << bj);
                int p = TT / bbin;
                p = p < 8 ? 8 : (p > 64 ? 64 : p);
                per[k]  = p;
                cycv[k] = TT / p;
                st[k]   = TT - cycv[k] * p;
            }
            if (tid == 0) {
                #pragma unroll
                for (int k = 0; k < KP; ++k) {
                    out[VOFF + (size_t)bn * KP + k]        = (float)per[k];
                    out[VOFF + 8192 + (size_t)bn * KP + k] = (float)cycv[k];
                }
            }
            float* outv = out + (size_t)bn * (KP * 64 * 64);
            const int c_local = tid >> 4;
            const int p0 = (tid & 15) << 2;
            #pragma unroll
            for (int it = 0; it < 16; ++it) {
                const int k = it >> 2;
                const int c = ((it & 3) << 4) + c_local;
                float4 v = make_float4(0.f, 0.f, 0.f, 0.f);
                const int P = per[k], C = cycv[k], S0 = st[k];
                if (c < C) {
                    const int base = S0 + c * P;
                    if (p0 + 3 < P) {
                        v.x = rowl[rr][base + p0];
                        v.y = rowl[rr][base + p0 + 1];
                        v.z = rowl[rr][base + p0 + 2];
                        v.w = rowl[rr][base + p0 + 3];
                    } else {
                        v.x = (p0 + 0 < P) ? rowl[rr][base + p0]     : 0.f;
                        v.y = (p0 + 1 < P) ? rowl[rr][base + p0 + 1] : 0.f;
                        v.z = (p0 + 2 < P) ? rowl[rr][base + p0 + 2] : 0.f;
                        v.w = (p0 + 3 < P) ? rowl[rr][base + p0 + 3] : 0.f;
                    }
                }
                *(float4*)(outv + (size_t)it * 1024 + (size_t)tid * 4) = v;
            }
        }
        // loop back: entry __syncthreads() makes LDS reuse safe; stores keep draining
    }
}

extern "C" void kernel_launch(void* const* d_in, const int* in_sizes, int n_in,
                              void* d_out, int out_size, void* d_ws, size_t ws_size,
                              hipStream_t stream) {
    const float* x = (const float*)d_in[0];
    float* out = (float*)d_out;
    hipLaunchKernelGGL(periodicity_kernel, dim3(512), dim3(256), 0, stream, x, out);
}